// Round 1
// baseline (61.037 us; speedup 1.0000x reference)
//
#include <hip/hip_runtime.h>
#include <math.h>

#define NB 16
#define NA 5
#define NC 20
#define NH 128
#define NW 128
#define MAXB 50
#define PLANE (NH * NW)      /* 16384 */
#define NCH 125              /* NA * (5 + NC) */
#define LOG20 2.99573227355399f

__device__ __constant__ float c_aw[NA] = {1.3221f, 3.19275f, 5.05587f, 9.47112f, 11.2364f};
__device__ __constant__ float c_ah[NA] = {1.73145f, 4.00944f, 8.09892f, 4.84053f, 10.0071f};

__device__ __forceinline__ float sigmoidf_(float x) {
    return 1.0f / (1.0f + __expf(-x));
}

// Kernel A: sum of sigmoid(conf)^2 over all (b, a, h, w) cells.
// Only reads the 5 conf planes per batch (channel a*25+4). 1280 blocks x 256
// threads x 1 float4 each == 327,680 float4 == 1,310,720 floats exactly.
__global__ __launch_bounds__(256) void conf_sum_kernel(const float* __restrict__ out,
                                                       float* __restrict__ acc) {
    int idx = blockIdx.x * 256 + threadIdx.x;
    float s = 0.0f;
    if (idx < NB * NA * (PLANE / 4)) {
        int p = idx >> 12;          // plane id 0..79 (4096 float4 per plane)
        int q = idx & 4095;
        int b = p / NA;
        int a = p - b * NA;
        const float4* src =
            (const float4*)(out + (size_t)(b * NCH + a * 25 + 4) * PLANE);
        float4 v = src[q];
        #pragma unroll
        for (int k = 0; k < 4; ++k) {
            float x = ((const float*)&v)[k];
            float c = sigmoidf_(x);
            s += c * c;
        }
    }
    // wave (64) reduce, then cross-wave via LDS, one atomic per block
    for (int off = 32; off; off >>= 1) s += __shfl_down(s, off, 64);
    __shared__ float wsum[4];
    int lane = threadIdx.x & 63, wv = threadIdx.x >> 6;
    if (lane == 0) wsum[wv] = s;
    __syncthreads();
    if (threadIdx.x == 0) {
        atomicAdd(acc, wsum[0] + wsum[1] + wsum[2] + wsum[3]);
    }
}

// Kernel B: one block, one thread per (batch, box). Computes validity
// (cumprod gx!=0), best-anchor IoU match, resolves duplicate scatters
// ("last box wins"), and accumulates the masked-cell loss corrections.
__global__ __launch_bounds__(1024) void box_kernel(const float* __restrict__ out,
                                                   const float* __restrict__ tgt,
                                                   float* __restrict__ acc,
                                                   int* __restrict__ ngt) {
    __shared__ float t[NB * MAXB * 5];   // 4000 floats = 16 KB
    __shared__ int cell[NB * MAXB];      // packed (a,j,i) or -1 if invalid
    for (int i = threadIdx.x; i < NB * MAXB * 5; i += 1024) t[i] = tgt[i];
    __syncthreads();

    int idx = threadIdx.x;
    float corr = 0.0f;
    int cnt = 0;
    int b = 0, k = 0, bi = 0, jj = 0, ii = 0;
    float gx = 0, gy = 0, gw = 0, gh = 0, cls_f = 0, best_iou = 0, ww = 0, hh = 0;
    bool valid = false;

    if (idx < NB * MAXB) {
        b = idx / MAXB;
        k = idx - b * MAXB;
        const float* tb = t + b * MAXB * 5;
        valid = true;
        for (int m = 0; m <= k; ++m) {
            if (tb[m * 5 + 1] == 0.0f) { valid = false; break; }
        }
        if (valid) {
            cnt = 1;
            cls_f = tb[k * 5 + 0];
            gx = tb[k * 5 + 1];
            gy = tb[k * 5 + 2];
            gw = tb[k * 5 + 3];
            gh = tb[k * 5 + 4];
            ii = min(max((int)(gx * NW), 0), NW - 1);
            jj = min(max((int)(gy * NH), 0), NH - 1);
            ww = gw * NW;
            hh = gh * NH;
            best_iou = -1.0f; bi = 0;
            #pragma unroll
            for (int a = 0; a < NA; ++a) {
                float inter = fminf(ww, c_aw[a]) * fminf(hh, c_ah[a]);
                float uni = ww * hh + c_aw[a] * c_ah[a] - inter;
                float iou = inter / uni;
                if (iou > best_iou) { best_iou = iou; bi = a; }
            }
            cell[idx] = (bi << 14) | (jj << 7) | ii;
        } else {
            cell[idx] = -1;
        }
    }
    __syncthreads();

    if (valid) {
        // last-wins survivor check among later valid boxes of same batch
        bool survivor = true;
        int my = cell[idx];
        for (int k2 = k + 1; k2 < MAXB; ++k2) {
            int c2 = cell[b * MAXB + k2];
            if (c2 < 0) break;             // validity is prefix-monotone
            if (c2 == my) { survivor = false; break; }
        }
        if (survivor) {
            const float* base = out + (size_t)(b * NCH + bi * 25) * PLANE + jj * NW + ii;
            float v[24];
            #pragma unroll
            for (int c = 0; c < 24; ++c) v[c] = base[(size_t)c * PLANE];
            float tx = gx * NW - (float)ii;
            float ty = gy * NH - (float)jj;
            float tw = logf(fmaxf(ww, 1e-12f) / c_aw[bi]);
            float th = logf(fmaxf(hh, 1e-12f) / c_ah[bi]);
            float sx = sigmoidf_(v[0]);
            float sy = sigmoidf_(v[1]);
            float sc = sigmoidf_(v[4]);
            // class slice is channels 4..23 (reference quirk: starts at conf)
            int tc = min(max((int)cls_f, 0), NC - 1);
            float m = v[4];
            #pragma unroll
            for (int c = 5; c < 24; ++c) m = fmaxf(m, v[c]);
            float se = 0.0f;
            #pragma unroll
            for (int c = 4; c < 24; ++c) se += __expf(v[c] - m);
            float nll = m + logf(se) - v[4 + tc];
            float dx = sx - tx, dy = sy - ty;
            float dw = v[2] - tw, dh = v[3] - th;
            float dc = sc - best_iou;
            corr = dx * dx + dy * dy + dw * dw + dh * dh
                 + 25.0f * dc * dc - sc * sc + (nll - LOG20);
        }
    }

    // block reduce corr (float) and cnt (int)
    for (int off = 32; off; off >>= 1) {
        corr += __shfl_down(corr, off, 64);
        cnt  += __shfl_down(cnt, off, 64);
    }
    __shared__ float rc[16];
    __shared__ int   ri[16];
    int lane = idx & 63, wv = idx >> 6;
    if (lane == 0) { rc[wv] = corr; ri[wv] = cnt; }
    __syncthreads();
    if (idx == 0) {
        float c = 0.0f; int n = 0;
        #pragma unroll
        for (int q = 0; q < 16; ++q) { c += rc[q]; n += ri[q]; }
        acc[1] = c;
        ngt[0] = n;
    }
}

__global__ void finalize_kernel(const float* __restrict__ acc,
                                const int* __restrict__ ngt,
                                float* __restrict__ out) {
    float n = fmaxf((float)ngt[0], 1.0f);
    out[0] = (acc[0] + acc[1] + (float)(NB * NA * NH * NW) * LOG20) / n;
}

extern "C" void kernel_launch(void* const* d_in, const int* in_sizes, int n_in,
                              void* d_out, int out_size, void* d_ws, size_t ws_size,
                              hipStream_t stream) {
    const float* output = (const float*)d_in[0];
    const float* target = (const float*)d_in[1];
    float* wsf = (float*)d_ws;      // [0]=conf^2 sum, [1]=corrections
    int* wsi = (int*)d_ws + 2;      // [0]=nGT
    hipMemsetAsync(d_ws, 0, 16, stream);

    int n_f4 = NB * NA * (PLANE / 4);               // 327,680
    int blocks = (n_f4 + 255) / 256;                // 1280
    conf_sum_kernel<<<blocks, 256, 0, stream>>>(output, wsf);
    box_kernel<<<1, 1024, 0, stream>>>(output, target, wsf, wsi);
    finalize_kernel<<<1, 1, 0, stream>>>(wsf, wsi, (float*)d_out);
}

// Round 2
// 41.963 us; speedup vs baseline: 1.4545x; 1.4545x over previous
//
#include <hip/hip_runtime.h>
#include <math.h>

#define NB 16
#define NA 5
#define NC 20
#define NH 128
#define NW 128
#define MAXB 50
#define PLANE (NH * NW)      /* 16384 */
#define NCH 125              /* NA * (5 + NC) */
#define LOG20 2.99573227355399f
#define BLOCKS_A 256         /* 256 blocks x 256 thr x 5 float4 = 327,680 */

__device__ __constant__ float c_aw[NA] = {1.3221f, 3.19275f, 5.05587f, 9.47112f, 11.2364f};
__device__ __constant__ float c_ah[NA] = {1.73145f, 4.00944f, 8.09892f, 4.84053f, 10.0071f};

__device__ __forceinline__ float sigmoidf_(float x) {
    return 1.0f / (1.0f + __expf(-x));
}

// Kernel A: sum of sigmoid(conf)^2 over all (b, a, h, w) cells.
// Reads only the 5 conf planes per batch. No atomics, no zero-init needed:
// each block fully overwrites part[blockIdx.x] every call.
__global__ __launch_bounds__(256) void conf_sum_kernel(const float* __restrict__ out,
                                                       float* __restrict__ part) {
    int tid = blockIdx.x * 256 + threadIdx.x;
    float s = 0.0f;
    #pragma unroll
    for (int it = 0; it < 5; ++it) {
        int idx = tid + it * (BLOCKS_A * 256);
        int p = idx >> 12;          // plane id 0..79 (4096 float4 per plane)
        int q = idx & 4095;
        int b = p / NA;
        int a = p - b * NA;
        const float4* src =
            (const float4*)(out + (size_t)(b * NCH + a * 25 + 4) * PLANE);
        float4 v = src[q];
        #pragma unroll
        for (int k = 0; k < 4; ++k) {
            float x = ((const float*)&v)[k];
            float c = sigmoidf_(x);
            s += c * c;
        }
    }
    for (int off = 32; off; off >>= 1) s += __shfl_down(s, off, 64);
    __shared__ float wsum[4];
    int lane = threadIdx.x & 63, wv = threadIdx.x >> 6;
    if (lane == 0) wsum[wv] = s;
    __syncthreads();
    if (threadIdx.x == 0) part[blockIdx.x] = wsum[0] + wsum[1] + wsum[2] + wsum[3];
}

// Kernel B: one block. Box matching + duplicate-scatter resolution +
// masked-cell corrections + reduction of kernel A's partials + finalize.
__global__ __launch_bounds__(1024) void box_finalize_kernel(const float* __restrict__ out,
                                                            const float* __restrict__ tgt,
                                                            const float* __restrict__ part,
                                                            float* __restrict__ result) {
    __shared__ float t[NB * MAXB * 5];   // 4000 floats = 16 KB
    __shared__ int cell[NB * MAXB];      // packed (a,j,i) or -1 if invalid
    for (int i = threadIdx.x; i < NB * MAXB * 5; i += 1024) t[i] = tgt[i];
    __syncthreads();

    int idx = threadIdx.x;
    float corr = (idx < BLOCKS_A) ? part[idx] : 0.0f;   // fold in conf^2 partials
    int cnt = 0;
    int b = 0, k = 0, bi = 0, jj = 0, ii = 0;
    float gx = 0, gy = 0, gw = 0, gh = 0, cls_f = 0, best_iou = 0, ww = 0, hh = 0;
    bool valid = false;

    if (idx < NB * MAXB) {
        b = idx / MAXB;
        k = idx - b * MAXB;
        const float* tb = t + b * MAXB * 5;
        valid = true;
        for (int m = 0; m <= k; ++m) {
            if (tb[m * 5 + 1] == 0.0f) { valid = false; break; }
        }
        if (valid) {
            cnt = 1;
            cls_f = tb[k * 5 + 0];
            gx = tb[k * 5 + 1];
            gy = tb[k * 5 + 2];
            gw = tb[k * 5 + 3];
            gh = tb[k * 5 + 4];
            ii = min(max((int)(gx * NW), 0), NW - 1);
            jj = min(max((int)(gy * NH), 0), NH - 1);
            ww = gw * NW;
            hh = gh * NH;
            best_iou = -1.0f; bi = 0;
            #pragma unroll
            for (int a = 0; a < NA; ++a) {
                float inter = fminf(ww, c_aw[a]) * fminf(hh, c_ah[a]);
                float uni = ww * hh + c_aw[a] * c_ah[a] - inter;
                float iou = inter / uni;
                if (iou > best_iou) { best_iou = iou; bi = a; }
            }
            cell[idx] = (bi << 14) | (jj << 7) | ii;
        } else {
            cell[idx] = -1;
        }
    }
    __syncthreads();

    if (valid) {
        // last-wins survivor check among later valid boxes of same batch
        bool survivor = true;
        int my = cell[idx];
        for (int k2 = k + 1; k2 < MAXB; ++k2) {
            int c2 = cell[b * MAXB + k2];
            if (c2 < 0) break;             // validity is prefix-monotone
            if (c2 == my) { survivor = false; break; }
        }
        if (survivor) {
            const float* base = out + (size_t)(b * NCH + bi * 25) * PLANE + jj * NW + ii;
            float v[24];
            #pragma unroll
            for (int c = 0; c < 24; ++c) v[c] = base[(size_t)c * PLANE];
            float tx = gx * NW - (float)ii;
            float ty = gy * NH - (float)jj;
            float tw = logf(fmaxf(ww, 1e-12f) / c_aw[bi]);
            float th = logf(fmaxf(hh, 1e-12f) / c_ah[bi]);
            float sx = sigmoidf_(v[0]);
            float sy = sigmoidf_(v[1]);
            float sc = sigmoidf_(v[4]);
            // class slice is channels 4..23 (reference quirk: starts at conf)
            int tc = min(max((int)cls_f, 0), NC - 1);
            float m = v[4];
            #pragma unroll
            for (int c = 5; c < 24; ++c) m = fmaxf(m, v[c]);
            float se = 0.0f;
            #pragma unroll
            for (int c = 4; c < 24; ++c) se += __expf(v[c] - m);
            float nll = m + logf(se) - v[4 + tc];
            float dx = sx - tx, dy = sy - ty;
            float dw = v[2] - tw, dh = v[3] - th;
            float dc = sc - best_iou;
            corr += dx * dx + dy * dy + dw * dw + dh * dh
                  + 25.0f * dc * dc - sc * sc + (nll - LOG20);
        }
    }

    // block reduce corr (float) and cnt (int) across 1024 threads
    for (int off = 32; off; off >>= 1) {
        corr += __shfl_down(corr, off, 64);
        cnt  += __shfl_down(cnt, off, 64);
    }
    __shared__ float rc[16];
    __shared__ int   ri[16];
    int lane = idx & 63, wv = idx >> 6;
    if (lane == 0) { rc[wv] = corr; ri[wv] = cnt; }
    __syncthreads();
    if (idx == 0) {
        float c = 0.0f; int n = 0;
        #pragma unroll
        for (int q = 0; q < 16; ++q) { c += rc[q]; n += ri[q]; }
        float nf = fmaxf((float)n, 1.0f);
        result[0] = (c + (float)(NB * NA * NH * NW) * LOG20) / nf;
    }
}

extern "C" void kernel_launch(void* const* d_in, const int* in_sizes, int n_in,
                              void* d_out, int out_size, void* d_ws, size_t ws_size,
                              hipStream_t stream) {
    const float* output = (const float*)d_in[0];
    const float* target = (const float*)d_in[1];
    float* part = (float*)d_ws;     // BLOCKS_A floats, fully overwritten per call

    conf_sum_kernel<<<BLOCKS_A, 256, 0, stream>>>(output, part);
    box_finalize_kernel<<<1, 1024, 0, stream>>>(output, target, part, (float*)d_out);
}

// Round 3
// 27.764 us; speedup vs baseline: 2.1984x; 1.5114x over previous
//
#include <hip/hip_runtime.h>
#include <math.h>

#define NB 16
#define NA 5
#define NC 20
#define NH 128
#define NW 128
#define MAXB 50
#define PLANE (NH * NW)      /* 16384 */
#define NCH 125              /* NA * (5 + NC) */
#define LOG20 2.99573227355399f
#define NBLK 256             /* blocks in kernel B2 */
#define NSLOT (NB * MAXB)    /* 800 survivor slots */

/* ws layout (4-byte units):
   [0]   ticket (int, zeroed by B1 each call)
   [1]   nGT (int)
   [2..257]   part[256] (float, fully overwritten each call via atomicExch)
   [260 + s*8 ...]  survivor record s: {base(int), tc(int), tx, ty, tw, th, tconf, pad}
*/
#define WS_TICKET 0
#define WS_NGT 1
#define WS_PART 2
#define WS_REC 260

__device__ __constant__ float c_aw[NA] = {1.3221f, 3.19275f, 5.05587f, 9.47112f, 11.2364f};
__device__ __constant__ float c_ah[NA] = {1.73145f, 4.00944f, 8.09892f, 4.84053f, 10.0071f};

__device__ __forceinline__ float sigmoidf_(float x) {
    return 1.0f / (1.0f + __expf(-x));
}

// B1: one block. Validity + anchor match + duplicate-scatter resolution.
// Writes survivor records + nGT, zeroes the ticket. No big global gather.
__global__ __launch_bounds__(1024) void match_kernel(const float* __restrict__ tgt,
                                                     float* __restrict__ wsf,
                                                     int* __restrict__ wsi) {
    __shared__ float t[NB * MAXB * 5];   // 16 KB
    __shared__ int cell[NSLOT];
    for (int i = threadIdx.x; i < NB * MAXB * 5; i += 1024) t[i] = tgt[i];
    __syncthreads();

    int idx = threadIdx.x;
    int cnt = 0;
    int b = 0, k = 0, bi = 0, jj = 0, ii = 0;
    float gx = 0, gy = 0, gw = 0, gh = 0, cls_f = 0, best_iou = 0, ww = 0, hh = 0;
    bool valid = false;

    if (idx < NSLOT) {
        b = idx / MAXB;
        k = idx - b * MAXB;
        const float* tb = t + b * MAXB * 5;
        valid = true;
        for (int m = 0; m <= k; ++m) {
            if (tb[m * 5 + 1] == 0.0f) { valid = false; break; }
        }
        if (valid) {
            cnt = 1;
            cls_f = tb[k * 5 + 0];
            gx = tb[k * 5 + 1];
            gy = tb[k * 5 + 2];
            gw = tb[k * 5 + 3];
            gh = tb[k * 5 + 4];
            ii = min(max((int)(gx * NW), 0), NW - 1);
            jj = min(max((int)(gy * NH), 0), NH - 1);
            ww = gw * NW;
            hh = gh * NH;
            best_iou = -1.0f; bi = 0;
            #pragma unroll
            for (int a = 0; a < NA; ++a) {
                float inter = fminf(ww, c_aw[a]) * fminf(hh, c_ah[a]);
                float uni = ww * hh + c_aw[a] * c_ah[a] - inter;
                float iou = inter / uni;
                if (iou > best_iou) { best_iou = iou; bi = a; }
            }
            cell[idx] = (bi << 14) | (jj << 7) | ii;
        } else {
            cell[idx] = -1;
        }
    }
    __syncthreads();

    if (idx < NSLOT) {
        bool survivor = false;
        if (valid) {
            survivor = true;
            int my = cell[idx];
            for (int k2 = k + 1; k2 < MAXB; ++k2) {
                int c2 = cell[b * MAXB + k2];
                if (c2 < 0) break;             // validity is prefix-monotone
                if (c2 == my) { survivor = false; break; }
            }
        }
        float* rf = wsf + WS_REC + idx * 8;
        int* ri = (int*)rf;
        if (survivor) {
            ri[0] = (b * NCH + bi * 25) * PLANE + jj * NW + ii;
            ri[1] = min(max((int)cls_f, 0), NC - 1);
            rf[2] = gx * NW - (float)ii;
            rf[3] = gy * NH - (float)jj;
            rf[4] = logf(fmaxf(ww, 1e-12f) / c_aw[bi]);
            rf[5] = logf(fmaxf(hh, 1e-12f) / c_ah[bi]);
            rf[6] = best_iou;
        } else {
            ri[0] = -1;
        }
    }

    // reduce cnt -> nGT; zero ticket
    for (int off = 32; off; off >>= 1) cnt += __shfl_down(cnt, off, 64);
    __shared__ int rci[16];
    int lane = idx & 63, wv = idx >> 6;
    if (lane == 0) rci[wv] = cnt;
    __syncthreads();
    if (idx == 0) {
        int n = 0;
        #pragma unroll
        for (int q = 0; q < 16; ++q) n += rci[q];
        wsi[WS_NGT] = n;
        wsi[WS_TICKET] = 0;
    }
}

// B2: 256 blocks x 256 threads. conf^2 sum (coalesced) + per-block survivor
// corrections (4 slots/block, parallel scattered gather) + last-block
// deterministic reduce + finalize.
__global__ __launch_bounds__(256) void sum_finalize_kernel(const float* __restrict__ out,
                                                           float* __restrict__ wsf,
                                                           int* __restrict__ wsi,
                                                           float* __restrict__ result) {
    int tid = threadIdx.x, bid = blockIdx.x;
    int gtid = bid * 256 + tid;
    float s = 0.0f;

    // conf^2 over the 5 conf planes: 256x256x5 float4 == exactly 327,680
    #pragma unroll
    for (int it = 0; it < 5; ++it) {
        int idx = gtid + it * (NBLK * 256);
        int p = idx >> 12;          // plane id 0..79
        int q = idx & 4095;
        int b = p / NA;
        int a = p - b * NA;
        const float4* src =
            (const float4*)(out + (size_t)(b * NCH + a * 25 + 4) * PLANE);
        float4 v = src[q];
        #pragma unroll
        for (int k = 0; k < 4; ++k) {
            float x = ((const float*)&v)[k];
            float c = sigmoidf_(x);
            s += c * c;
        }
    }

    // survivor corrections: 4 slots per block
    if (tid < 4) {
        int slot = bid * 4 + tid;
        if (slot < NSLOT) {
            const float* rf = wsf + WS_REC + slot * 8;
            const int* ri = (const int*)rf;
            int base = ri[0];
            if (base >= 0) {
                int tc = ri[1];
                float tx = rf[2], ty = rf[3], tw = rf[4], th = rf[5], tconf = rf[6];
                float v[24];
                #pragma unroll
                for (int c = 0; c < 24; ++c) v[c] = out[(size_t)base + (size_t)c * PLANE];
                float sx = sigmoidf_(v[0]);
                float sy = sigmoidf_(v[1]);
                float sc = sigmoidf_(v[4]);
                float m = v[4];
                #pragma unroll
                for (int c = 5; c < 24; ++c) m = fmaxf(m, v[c]);
                float se = 0.0f;
                #pragma unroll
                for (int c = 4; c < 24; ++c) se += __expf(v[c] - m);
                float nll = m + logf(se) - v[4 + tc];
                float dx = sx - tx, dy = sy - ty;
                float dw = v[2] - tw, dh = v[3] - th;
                float dc = sc - tconf;
                s += dx * dx + dy * dy + dw * dw + dh * dh
                   + 25.0f * dc * dc - sc * sc + (nll - LOG20);
            }
        }
    }

    // block reduce (4 waves)
    for (int off = 32; off; off >>= 1) s += __shfl_down(s, off, 64);
    __shared__ float wsum[4];
    __shared__ int lastflag;
    int lane = tid & 63, wv = tid >> 6;
    if (lane == 0) wsum[wv] = s;
    __syncthreads();
    if (tid == 0) {
        float partial = wsum[0] + wsum[1] + wsum[2] + wsum[3];
        atomicExch(&wsf[WS_PART + bid], partial);   // coherent publish
        __threadfence();
        int t = atomicAdd(&wsi[WS_TICKET], 1);
        lastflag = (t == NBLK - 1) ? 1 : 0;
    }
    __syncthreads();

    if (lastflag) {
        // deterministic tree reduce of the 256 partials (coherent atomic reads)
        float v = atomicAdd(&wsf[WS_PART + tid], 0.0f);
        for (int off = 32; off; off >>= 1) v += __shfl_down(v, off, 64);
        __shared__ float fsum[4];
        if (lane == 0) fsum[wv] = v;
        __syncthreads();
        if (tid == 0) {
            float total = fsum[0] + fsum[1] + fsum[2] + fsum[3];
            float nf = fmaxf((float)wsi[WS_NGT], 1.0f);
            result[0] = (total + (float)(NB * NA * NH * NW) * LOG20) / nf;
        }
    }
}

extern "C" void kernel_launch(void* const* d_in, const int* in_sizes, int n_in,
                              void* d_out, int out_size, void* d_ws, size_t ws_size,
                              hipStream_t stream) {
    const float* output = (const float*)d_in[0];
    const float* target = (const float*)d_in[1];
    float* wsf = (float*)d_ws;
    int* wsi = (int*)d_ws;

    match_kernel<<<1, 1024, 0, stream>>>(target, wsf, wsi);
    sum_finalize_kernel<<<NBLK, 256, 0, stream>>>(output, wsf, wsi, (float*)d_out);
}